// Round 10
// baseline (350.195 us; speedup 1.0000x reference)
//
#include <hip/hip_runtime.h>
#include <math.h>

#define N0c   16
#define NAt   96
#define ORIG  92
#define Fc    64
#define Kc    41
#define Hc    128
#define NCc   3
#define C2    128   // 2F
#define EPSBN 1e-5f
#define JG    4
#define JPW   (NAt / JG)
#define NREP  32    // atomic replica slots
#define FP    16    // f-pairs per k_apply block (f-quarter)
#define INV1  (1.f / (float)(N0c * NAt * NAt))
#define INV2  (1.f / (float)(N0c * NAt))

__device__ __forceinline__ float sp_(float x){
    return fmaxf(x, 0.f) + __logf(1.f + __expf(-fabsf(x)));
}
__device__ __forceinline__ float sgm_(float x){
    return 1.f / (1.f + __expf(-x));
}

// fea = atom @ emb_W + emb_b
__global__ __launch_bounds__(256) void k_embed(const float* __restrict__ atom,
                                               const float* __restrict__ W,
                                               const float* __restrict__ b,
                                               float* __restrict__ fea){
    int row = blockIdx.x * 4 + (threadIdx.x >> 6);
    int f   = threadIdx.x & 63;
    const float* ar = atom + row * ORIG;
    float acc = b[f];
    #pragma unroll 4
    for (int o = 0; o < ORIG; ++o) acc += ar[o] * W[o * Fc + f];
    fea[row * Fc + f] = acc;
}

// One-time: S_r, T_r, cnt_r.
__global__ __launch_bounds__(256) void k_pre(const float* __restrict__ nbr,
                                             const int*   __restrict__ adj,
                                             float* __restrict__ ST,
                                             float* __restrict__ cntf){
    int r    = blockIdx.x;
    int lane = threadIdx.x & 63;
    int jg   = __builtin_amdgcn_readfirstlane(threadIdx.x >> 6);
    __shared__ float rS[JG][Kc], rT[JG][Kc], rc[JG];
    float S = 0.f, T = 0.f, cn = 0.f;
    int j0 = jg * JPW;
    for (int j = j0; j < j0 + JPW; ++j){
        float a = (float)adj[r * NAt + j];
        float v = (lane < Kc) ? nbr[((size_t)r * NAt + j) * Kc + lane] : 0.f;
        S += v; T += a * v; cn += a;
    }
    if (lane < Kc){ rS[jg][lane] = S; rT[jg][lane] = T; }
    if (lane == 0) rc[jg] = cn;
    __syncthreads();
    int t = threadIdx.x;
    if (t < Kc){
        ST[r * (2 * Kc) + t]      = rS[0][t] + rS[1][t] + rS[2][t] + rS[3][t];
        ST[r * (2 * Kc) + Kc + t] = rT[0][t] + rT[1][t] + rT[2][t] + rT[3][t];
    }
    if (t == 0) cntf[r] = rc[0] + rc[1] + rc[2] + rc[3];
}

// Gram partials: rpb r's per block, private partial per block (no atomics).
__global__ __launch_bounds__(128) void k_gram(const float* __restrict__ nbr,
                                              float* __restrict__ pG, int rpb){
    int blk = blockIdx.x;
    int t   = threadIdx.x;
    int k   = (t % 21) * 2;
    int lb  = (t / 21) * 7;
    __shared__ float L[NAt * Kc];                    // 15.7 KB
    float a0[7] = {0,0,0,0,0,0,0}, a1[7] = {0,0,0,0,0,0,0};
    for (int rr = 0; rr < rpb; ++rr){
        int r = blk * rpb + rr;
        __syncthreads();
        for (int i = t; i < NAt * Kc; i += 128)
            L[i] = nbr[(size_t)r * NAt * Kc + i];
        __syncthreads();
        if (t < 126){
            for (int j = 0; j < NAt; ++j){
                float vk0 = L[j * Kc + k];
                float vk1 = (k + 1 < Kc) ? L[j * Kc + k + 1] : 0.f;
                #pragma unroll
                for (int m = 0; m < 7; ++m){
                    if (lb + m < Kc){
                        float lv = L[j * Kc + lb + m];
                        a0[m] += vk0 * lv;
                        a1[m] += vk1 * lv;
                    }
                }
            }
        }
    }
    if (t < 126){
        float* dst = pG + (size_t)blk * (Kc * Kc);
        #pragma unroll
        for (int m = 0; m < 7; ++m){
            if (lb + m < Kc){
                dst[k * Kc + lb + m] = a0[m];
                if (k + 1 < Kc) dst[(k + 1) * Kc + lb + m] = a1[m];
            }
        }
    }
}

// Phased partial reduce.
__global__ __launch_bounds__(64) void k_gred(const float* __restrict__ pG,
                                             float* __restrict__ G){
    int i  = (blockIdx.x % 27) * 64 + threadIdx.x;
    int b0 = (blockIdx.x / 27) * 96;
    if (i < Kc * Kc){
        float s = 0.f;
        #pragma unroll 4
        for (int b = b0; b < b0 + 96; ++b) s += pG[(size_t)b * (Kc * Kc) + i];
        atomicAdd(&G[i], s);
    }
}

// One-time: transposed padded W3: W3T[l][c][44]
__global__ void k_wt(const float* __restrict__ convW, float* __restrict__ W3T){
    int l = blockIdx.x, c = threadIdx.x;
    const float* Wl = convW + (size_t)l * 169 * C2;
    float* dst = W3T + ((size_t)l * C2 + c) * 44;
    for (int k = 0; k < Kc; ++k) dst[k] = Wl[(C2 + k) * C2 + c];
    dst[41] = 0.f; dst[42] = 0.f; dst[43] = 0.f;
}

// One-time: q3[l][c] = w3^T G w3
__global__ __launch_bounds__(128) void k_quad(const float* __restrict__ G,
                                              const float* __restrict__ convW,
                                              float* __restrict__ q3){
    int l = blockIdx.x, c = threadIdx.x;
    const float* Wl = convW + (size_t)l * 169 * C2;
    __shared__ float GL[Kc * Kc];
    for (int i = c; i < Kc * Kc; i += 128) GL[i] = G[i];
    float w3[Kc];
    #pragma unroll
    for (int k = 0; k < Kc; ++k) w3[k] = Wl[(C2 + k) * C2 + c];
    __syncthreads();
    float q = 0.f;
    for (int k = 0; k < Kc; ++k){
        float gw = 0.f;
        #pragma unroll
        for (int m = 0; m < Kc; ++m) gw += GL[k * Kc + m] * w3[m];
        q += w3[k] * gw;
    }
    q3[l * C2 + c] = q;
}

// Fused p12 + closed-form BN1 stats, ONE row per block (grid 1536).
// waves_per_eu max=4 -> 128-VGPR budget, keeps w3[41] in arch VGPRs.
__global__ __launch_bounds__(128)
__attribute__((amdgpu_waves_per_eu(2, 4)))
void k_front(const float* __restrict__ fea,
             const float* __restrict__ Wl,
             const float* __restrict__ bl,
             const float* __restrict__ W3Tl,
             const float* __restrict__ ST,
             const float* __restrict__ cntf,
             float* __restrict__ p1,
             float* __restrict__ p2,
             float* __restrict__ sum1R,
             float* __restrict__ sq1R){
    int c = threadIdx.x;
    int r = blockIdx.x;
    float w3[Kc];
    const float* wt = W3Tl + c * 44;
    #pragma unroll
    for (int k = 0; k < 40; k += 4){
        float4 v = *(const float4*)(wt + k);
        w3[k] = v.x; w3[k+1] = v.y; w3[k+2] = v.z; w3[k+3] = v.w;
    }
    w3[40] = wt[40];
    const float* fr = fea + r * Fc;
    float a1 = bl[c], a2 = 0.f;
    #pragma unroll 8
    for (int f = 0; f < Fc; ++f){
        float fv = fr[f];              // uniform -> s_load
        a1 += fv * Wl[f * C2 + c];
        a2 += fv * Wl[(Fc + f) * C2 + c];
    }
    p1[r * C2 + c] = a1;
    p2[r * C2 + c] = a2;
    const float* Sr = ST + r * (2 * Kc);   // uniform -> s_loads
    const float* Tr = Sr + Kc;
    float u = 0.f, tt = 0.f;
    #pragma unroll
    for (int k = 0; k < Kc; ++k){ u += Sr[k] * w3[k]; tt += Tr[k] * w3[k]; }
    float cn = cntf[r];
    float s1 = (float)NAt * a1 + cn * a2 + u;
    float q1 = (float)NAt * a1 * a1 + cn * a2 * a2
             + 2.f * cn * a1 * a2 + 2.f * a1 * u + 2.f * a2 * tt;
    int slot = blockIdx.x & (NREP - 1);
    atomicAdd(&sum1R[slot * C2 + c], s1);
    atomicAdd(&sq1R[slot * C2 + c], q1);
}

// Pass 2 v5: thread owns one j-row (nr[41] in VGPRs), 16 f-pairs per block
// (grid = 1536*2). waves_per_eu(2,4) -> 128-VGPR budget: stops the
// allocator's max-occupancy heuristic from AGPR-offloading nr[] (R9: VGPR=32
// with 41-elem array = accvgpr_read per use).
__global__ __launch_bounds__(192)
__attribute__((amdgpu_waves_per_eu(2, 4)))
void k_apply(const float* __restrict__ nbr,
             const int*   __restrict__ adj,
             const float* __restrict__ w3t,
             const float* __restrict__ p1,
             const float* __restrict__ p2,
             const float* __restrict__ sum1R,
             const float* __restrict__ sq1R,
             const float* __restrict__ qv,
             const float* __restrict__ g1,
             const float* __restrict__ b1,
             float* __restrict__ summed,
             float* __restrict__ sum2R,
             float* __restrict__ sq2R){
    int tid = threadIdx.x;
    int fq  = blockIdx.x & 3;        // f-quarter
    int pr  = blockIdx.x >> 2;
    int f0  = fq * FP;
    int bi0 = pr * 2;
    __shared__ float ABf[4][FP];     // A1,B1,A2,B2
    __shared__ float PL[2][4][FP];   // pa1,pa2,pb1,pb2 per bi
    __shared__ float Tp[6][FP];      // halfgroup partials

    if (tid < 32){                   // fold BN1 finalize (replica reduce)
        int half = tid >> 4, fi = tid & (FP - 1);
        int c = half * 64 + f0 + fi;
        float s = 0.f, q = 0.f;
        for (int r = 0; r < NREP; ++r){ s += sum1R[r * C2 + c]; q += sq1R[r * C2 + c]; }
        float m = s * INV1;
        float v = (q + qv[c]) * INV1 - m * m;
        float A = g1[c] * rsqrtf(v + EPSBN);
        ABf[half * 2 + 0][fi] = A;
        ABf[half * 2 + 1][fi] = b1[c] - m * A;
    } else if (tid >= 64){           // stage p1/p2 fragments (128 threads)
        int vv  = tid - 64;
        int bl_ = vv >> 6, rem = vv & 63, arr = rem >> 4, fi = rem & (FP - 1);
        int r = bi0 + bl_;
        int c = ((arr & 2) ? 64 : 0) + f0 + fi;
        const float* src = (arr & 1) ? p2 : p1;
        PL[bl_][arr][fi] = src[r * C2 + c];
    }
    int bi_l = (tid >= 96) ? 1 : 0;
    int j    = tid - bi_l * 96;
    int bi   = bi0 + bi_l;
    float ajf = (float)adj[bi * NAt + j];
    float nr[Kc];
    const float* nrow = nbr + ((size_t)bi * NAt + j) * Kc;
    #pragma unroll
    for (int k = 0; k < Kc; ++k) nr[k] = nrow[k];
    __syncthreads();

    int hg = tid >> 5;
    #pragma unroll 2
    for (int f = 0; f < FP; ++f){
        const float* wA = w3t + (f0 + f) * 44;        // uniform -> s_loads
        const float* wB = w3t + (64 + f0 + f) * 44;
        float d0 = 0.f, d1 = 0.f, e0 = 0.f, e1 = 0.f;
        #pragma unroll
        for (int k = 0; k < 40; k += 2){
            d0 += nr[k] * wA[k];     d1 += nr[k+1] * wA[k+1];
            e0 += nr[k] * wB[k];     e1 += nr[k+1] * wB[k+1];
        }
        d0 += nr[40] * wA[40];
        e0 += nr[40] * wB[40];
        float gf = (PL[bi_l][0][f] + ajf * PL[bi_l][1][f] + (d0 + d1)) * ABf[0][f] + ABf[1][f];
        float gc = (PL[bi_l][2][f] + ajf * PL[bi_l][3][f] + (e0 + e1)) * ABf[2][f] + ABf[3][f];
        float t = sgm_(gf) * sp_(gc);
        t += __shfl_xor(t, 1);  t += __shfl_xor(t, 2);  t += __shfl_xor(t, 4);
        t += __shfl_xor(t, 8);  t += __shfl_xor(t, 16);
        if ((tid & 31) == 0) Tp[hg][f] = t;
    }
    __syncthreads();
    if (tid < 32){
        int bl_ = tid >> 4, fi = tid & (FP - 1);
        float s = Tp[bl_ * 3 + 0][fi] + Tp[bl_ * 3 + 1][fi] + Tp[bl_ * 3 + 2][fi];
        summed[(bi0 + bl_) * Fc + f0 + fi] = s;
        int slot = blockIdx.x & (NREP - 1);
        atomicAdd(&sum2R[slot * Fc + f0 + fi], s);
        atomicAdd(&sq2R[slot * Fc + f0 + fi], s * s);
    }
}

// fea = softplus(fea + BN2(summed)), BN2 finalize folded in.
__global__ __launch_bounds__(256) void k_update(float* __restrict__ fea,
                                                const float* __restrict__ summed,
                                                const float* __restrict__ sum2R,
                                                const float* __restrict__ sq2R,
                                                const float* __restrict__ g2,
                                                const float* __restrict__ b2){
    __shared__ float A2L[Fc], B2L[Fc];
    int tid = threadIdx.x;
    if (tid < Fc){
        float s = 0.f, q = 0.f;
        for (int r = 0; r < NREP; ++r){ s += sum2R[r * Fc + tid]; q += sq2R[r * Fc + tid]; }
        float m = s * INV2;
        float v = q * INV2 - m * m;
        float A = g2[tid] * rsqrtf(v + EPSBN);
        A2L[tid] = A;
        B2L[tid] = b2[tid] - m * A;
    }
    __syncthreads();
    int idx = blockIdx.x * 256 + tid;
    int f   = idx & 63;
    fea[idx] = sp_(fea[idx] + summed[idx] * A2L[f] + B2L[f]);
}

// crys = mean_i fea; out = softplus(softplus(crys)@fcW + fcb) @ outW + outb
__global__ __launch_bounds__(128) void k_final(const float* __restrict__ fea,
                                               const float* __restrict__ fcW,
                                               const float* __restrict__ fcb,
                                               const float* __restrict__ outW,
                                               const float* __restrict__ outb,
                                               float* __restrict__ out){
    int b = blockIdx.x;
    int t = threadIdx.x;
    __shared__ float spc[Fc];
    __shared__ float red[Hc];
    if (t < Fc){
        float s = 0.f;
        for (int i = 0; i < NAt; ++i) s += fea[(b * NAt + i) * Fc + t];
        spc[t] = sp_(s * (1.f / NAt));
    }
    __syncthreads();
    float h = fcb[t];
    #pragma unroll 4
    for (int f = 0; f < Fc; ++f) h += spc[f] * fcW[f * Hc + t];
    h = sp_(h);
    red[t] = h * outW[t];
    __syncthreads();
    for (int off = 64; off > 0; off >>= 1){
        if (t < off) red[t] += red[t + off];
        __syncthreads();
    }
    if (t == 0) out[b] = red[0] + outb[0];
}

extern "C" void kernel_launch(void* const* d_in, const int* in_sizes, int n_in,
                              void* d_out, int out_size, void* d_ws, size_t ws_size,
                              hipStream_t stream){
    const float* atom  = (const float*)d_in[0];
    const float* nbr   = (const float*)d_in[1];
    const int*   adj   = (const int*)  d_in[2];
    const float* embW  = (const float*)d_in[3];
    const float* embB  = (const float*)d_in[4];
    const float* convW = (const float*)d_in[5];
    const float* convB = (const float*)d_in[6];
    const float* bn1g  = (const float*)d_in[7];
    const float* bn1b  = (const float*)d_in[8];
    const float* bn2g  = (const float*)d_in[9];
    const float* bn2b  = (const float*)d_in[10];
    const float* fcW   = (const float*)d_in[11];
    const float* fcb   = (const float*)d_in[12];
    const float* outW  = (const float*)d_in[13];
    const float* outb  = (const float*)d_in[14];
    float* out = (float*)d_out;
    float* ws  = (float*)d_ws;

    const int ROWS = N0c * NAt;            // 1536
    float* fea    = ws;                    // 98304
    float* p1     = ws + 98304;            // 196608
    float* p2     = ws + 294912;           // 196608
    float* summed = ws + 491520;           // 98304
    float* SR     = ws + 589824;           // 12288 replica stats
    float* sum1R = SR;          float* sq1R = SR + 4096;
    float* sum2R = SR + 8192;   float* sq2R = SR + 10240;
    float* ST     = ws + 602112;           // 125952
    float* cntf   = ws + 728064;           // 1536
    float* q3     = ws + 729600;           // 384
    float* W3T    = ws + 729984;           // 16896 -> PERS end 746880
    const size_t PERS = 746880;

    size_t ws_f = ws_size / sizeof(float);
    int nblk; float *pG, *G;
    if (ws_f >= PERS + (size_t)1536 * 1681 + 1681 + 64){
        nblk = 1536; pG = ws + PERS; G = pG + (size_t)nblk * 1681;
    } else if (ws_f >= PERS + (size_t)768 * 1681 + 1681 + 64){
        nblk = 768;  pG = ws + PERS; G = pG + (size_t)nblk * 1681;
    } else if (ws_f >= PERS + (size_t)384 * 1681 + 1681 + 64){
        nblk = 384;  pG = ws + PERS; G = pG + (size_t)nblk * 1681;
    } else {
        nblk = 384;  pG = ws;        G = ws + 650000;
    }
    int rpb = 1536 / nblk;
    int ph  = nblk / 96;

    hipMemsetAsync(G, 0, Kc * Kc * sizeof(float), stream);
    k_gram <<<nblk, 128, 0, stream>>>(nbr, pG, rpb);
    k_gred <<<27 * ph, 64, 0, stream>>>(pG, G);
    k_wt   <<<NCc, C2, 0, stream>>>(convW, W3T);
    k_quad <<<NCc, C2, 0, stream>>>(G, convW, q3);
    k_embed<<<ROWS / 4, 256, 0, stream>>>(atom, embW, embB, fea);
    k_pre  <<<ROWS, 256, 0, stream>>>(nbr, adj, ST, cntf);

    for (int l = 0; l < NCc; ++l){
        const float* Wl   = convW + (size_t)l * 169 * C2;
        const float* bl   = convB + l * C2;
        const float* W3Tl = W3T + (size_t)l * C2 * 44;
        hipMemsetAsync(SR, 0, 12288 * sizeof(float), stream);
        k_front <<<ROWS, C2, 0, stream>>>(fea, Wl, bl, W3Tl, ST, cntf,
                                          p1, p2, sum1R, sq1R);
        k_apply <<<ROWS * 2, 192, 0, stream>>>(nbr, adj, W3Tl, p1, p2,
                                               sum1R, sq1R, q3 + l * C2,
                                               bn1g + l * C2, bn1b + l * C2,
                                               summed, sum2R, sq2R);
        k_update<<<ROWS * Fc / 256, 256, 0, stream>>>(fea, summed, sum2R, sq2R,
                                                      bn2g + l * Fc, bn2b + l * Fc);
    }

    k_final<<<N0c, Hc, 0, stream>>>(fea, fcW, fcb, outW, outb, out);
}